// Round 10
// baseline (336.309 us; speedup 1.0000x reference)
//
#include <hip/hip_runtime.h>
#include <hip/hip_bf16.h>

#define N_NODES 10000
#define N_EDGES 100000
#define D 248
#define DP 256      // padded D
#define HDIM 512
#define NNZ 2480
#define LN_EPS 1e-5f
#define PAD_ROWS 128  // row padding so async A-staging never reads outside its buffer

typedef __attribute__((ext_vector_type(8))) short bf16x8_t;
typedef __attribute__((ext_vector_type(4))) float f32x4_t;

__device__ __forceinline__ float bf2f(unsigned short u) {
  unsigned int x = ((unsigned int)u) << 16;
  return __builtin_bit_cast(float, x);
}
__device__ __forceinline__ unsigned short f2bf(float f) {
  return __builtin_bit_cast(unsigned short, __float2bfloat16(f));
}
__device__ __forceinline__ float bflo(unsigned int w) {
  return __builtin_bit_cast(float, w << 16);
}
__device__ __forceinline__ float bfhi(unsigned int w) {
  return __builtin_bit_cast(float, w & 0xFFFF0000u);
}
__device__ __forceinline__ void gload_lds16(const unsigned short* gp,
                                            unsigned short* lds_base) {
  __builtin_amdgcn_global_load_lds(
      (const __attribute__((address_space(1))) void*)gp,
      (__attribute__((address_space(3))) void*)lds_base, 16, 0, 0);
}

// ---------------------------------------------------------------------------
// Fused prep: feature+weight bf16 casts, deg zero, triple CSR by K.
// ---------------------------------------------------------------------------
#define CAST_BLOCKS (N_NODES + DP + HDIM + DP)
#define ZERO_BLOCKS 40
#define PREP_BLOCKS (CAST_BLOCKS + ZERO_BLOCKS + 1)

__device__ __forceinline__ void cast_row(const float* src, __hip_bfloat16* dst,
                                         int r, int sr, int sc, int dc) {
  for (int c = threadIdx.x; c < dc; c += 256) {
    float v = (r < sr && c < sc) ? src[(size_t)r * sc + c] : 0.f;
    dst[(size_t)r * dc + c] = __float2bfloat16(v);
  }
}

__global__ __launch_bounds__(256) void prep_kernel(
    const float* __restrict__ features, const float* __restrict__ W_msg,
    const float* __restrict__ W1, const float* __restrict__ W2,
    __hip_bfloat16* __restrict__ featB, __hip_bfloat16* __restrict__ WmB,
    __hip_bfloat16* __restrict__ W1B, __hip_bfloat16* __restrict__ W2B,
    int* __restrict__ deg,
    const int* __restrict__ Iv, const int* __restrict__ Jv,
    const int* __restrict__ Kv, const float* __restrict__ Cv,
    int* __restrict__ rsK, int2* __restrict__ trip) {
  const int b = blockIdx.x;
  if (b < N_NODES) {
    cast_row(features, featB, b, N_NODES, D, DP);
  } else if (b < N_NODES + DP) {
    cast_row(W_msg, WmB, b - N_NODES, D, D, DP);
  } else if (b < N_NODES + DP + HDIM) {
    cast_row(W1, W1B, b - N_NODES - DP, HDIM, D, DP);
  } else if (b < CAST_BLOCKS) {
    cast_row(W2, W2B, b - N_NODES - DP - HDIM, D, HDIM, HDIM);
  } else if (b < CAST_BLOCKS + ZERO_BLOCKS) {
    int i = (b - CAST_BLOCKS) * 256 + threadIdx.x;
    if (i < N_NODES) deg[i] = 0;
  } else {
    __shared__ int cnt[D];
    __shared__ int off[D];
    const int tid = threadIdx.x;
    for (int k = tid; k < D; k += 256) cnt[k] = 0;
    __syncthreads();
    for (int t = tid; t < NNZ; t += 256) atomicAdd(&cnt[Kv[t]], 1);
    __syncthreads();
    if (tid == 0) {
      int run = 0;
      for (int k = 0; k < D; k++) { off[k] = run; rsK[k] = run; run += cnt[k]; }
      rsK[D] = run;
    }
    __syncthreads();
    for (int t = tid; t < NNZ; t += 256) {
      int pos = atomicAdd(&off[Kv[t]], 1);
      trip[pos] = make_int2((Jv[t] << 16) | Iv[t], __float_as_int(Cv[t]));
    }
  }
}

// ---------------------------------------------------------------------------
// Edge CSR-by-target: histogram -> scan -> placement
// ---------------------------------------------------------------------------
__global__ __launch_bounds__(256) void hist_tgt(
    const int* __restrict__ ei, int* __restrict__ deg) {
  int e = blockIdx.x * 256 + threadIdx.x;
  if (e < N_EDGES) atomicAdd(&deg[ei[N_EDGES + e]], 1);
}

__global__ __launch_bounds__(256) void scan_deg(
    const int* __restrict__ deg, int* __restrict__ rs, int* __restrict__ woff) {
  __shared__ int part[256];
  const int t = threadIdx.x;
  const int base = t * 40;
  int sum = 0;
  for (int i = 0; i < 40; i++) {
    int idx = base + i;
    if (idx < N_NODES) sum += deg[idx];
  }
  part[t] = sum;
  __syncthreads();
  if (t == 0) {
    int run = 0;
    for (int i = 0; i < 256; i++) { int tmp = part[i]; part[i] = run; run += tmp; }
    rs[N_NODES] = run;
  }
  __syncthreads();
  int run = part[t];
  for (int i = 0; i < 40; i++) {
    int idx = base + i;
    if (idx < N_NODES) { rs[idx] = run; woff[idx] = run; run += deg[idx]; }
  }
}

__global__ __launch_bounds__(256) void place_edges(
    const int* __restrict__ ei, int* __restrict__ woff, int* __restrict__ esrc) {
  int e = blockIdx.x * 256 + threadIdx.x;
  if (e < N_EDGES) {
    int pos = atomicAdd(&woff[ei[N_EDGES + e]], 1);
    esrc[pos] = ei[e];
  }
}

// ---------------------------------------------------------------------------
// Gather bf16 rows (R8-identical): G[n] = sum_{e: tgt=n} featB[src(e)]
// ---------------------------------------------------------------------------
__global__ __launch_bounds__(256) void gather_G(
    const unsigned short* __restrict__ FB, const int* __restrict__ rs,
    const int* __restrict__ esrc, unsigned short* __restrict__ G) {
  const int tid = threadIdx.x;
  const int wv = tid >> 6;
  const int lane = tid & 63;
  const int half = lane >> 5;
  const int c = lane & 31;
  const int n = blockIdx.x * 4 + wv;

  const int beg = rs[n];
  const int deg = rs[n + 1] - beg;
  int eid = (lane < deg) ? esrc[beg + lane] : 0;

  float a[8] = {0.f, 0.f, 0.f, 0.f, 0.f, 0.f, 0.f, 0.f};
  const unsigned short* FBc = FB + (size_t)c * 8;
  int j = half;
  for (; j + 2 < deg && j < 64; j += 2) {
    int s = __shfl(eid, j);
    uint4 u = *(const uint4*)(FBc + (size_t)s * DP);
    a[0] += bflo(u.x); a[1] += bfhi(u.x);
    a[2] += bflo(u.y); a[3] += bfhi(u.y);
    a[4] += bflo(u.z); a[5] += bfhi(u.z);
    a[6] += bflo(u.w); a[7] += bfhi(u.w);
  }
  for (; j < deg; j += 2) {
    int s = (j < 64) ? __shfl(eid, j) : esrc[beg + j];
    uint4 u = *(const uint4*)(FBc + (size_t)s * DP);
    a[0] += bflo(u.x); a[1] += bfhi(u.x);
    a[2] += bflo(u.y); a[3] += bfhi(u.y);
    a[4] += bflo(u.z); a[5] += bfhi(u.z);
    a[6] += bflo(u.w); a[7] += bfhi(u.w);
  }
#pragma unroll
  for (int i = 0; i < 8; i++) a[i] += __shfl_xor(a[i], 32);

  if (half == 0) {
    uint4 o;
    o.x = (unsigned)f2bf(a[0]) | ((unsigned)f2bf(a[1]) << 16);
    o.y = (unsigned)f2bf(a[2]) | ((unsigned)f2bf(a[3]) << 16);
    o.z = (unsigned)f2bf(a[4]) | ((unsigned)f2bf(a[5]) << 16);
    o.w = (unsigned)f2bf(a[6]) | ((unsigned)f2bf(a[7]) << 16);
    *(uint4*)(G + (size_t)n * DP + c * 8) = o;
  }
}

// ---------------------------------------------------------------------------
// Fused GEMM1 + bracket. Tile 64x256 (full width), K=256 in 4 chunks.
//   S = G @ Wm^T (kept in LDS bf16) ; agg = bracket(S, featB) -> global bf16
// LDS 64 KB: K-phase {As 8K | Ws 32K} -> bracket-phase {sS 32K | sF 32K}.
// Grid 157 blocks; occupancy 2 blocks/CU by LDS (grid < 256 anyway).
// ---------------------------------------------------------------------------
__global__ __launch_bounds__(256) void gemm1_bracket(
    const unsigned short* __restrict__ G, const unsigned short* __restrict__ featB,
    const unsigned short* __restrict__ WmB,
    const int* __restrict__ rsK, const int2* __restrict__ trip,
    __hip_bfloat16* __restrict__ agg) {
  __shared__ __align__(16) unsigned short lds[32768];  // 64 KB
  unsigned short* As = lds;          // 64x64 bf16 (8 KB)
  unsigned short* Ws = lds + 4096;   // 256x64 bf16 (32 KB)
  unsigned short* sS = lds;          // 64x256 bf16 (32 KB) after K-loop
  unsigned short* sF = lds + 16384;  // 64x256 bf16 (32 KB)

  const int tid = threadIdx.x;
  const int wave = tid >> 6;
  const int lane = tid & 63;
  const int ml = lane & 15;
  const int q = lane >> 4;
  const int srow = lane >> 3, sg = lane & 7;
  const int m0 = blockIdx.x * 64;

  f32x4_t acc[4][4];
#pragma unroll
  for (int im = 0; im < 4; im++)
#pragma unroll
    for (int jn = 0; jn < 4; jn++) acc[im][jn] = (f32x4_t)0.f;

  for (int ch = 0; ch < 4; ch++) {
    const int k0 = ch * 64;
    // A: 64 rows x 64 cols, 8 insts (2/wave)
#pragma unroll
    for (int i = 0; i < 2; i++) {
      int t = wave * 2 + i;
      gload_lds16(G + (size_t)(m0 + t * 8 + srow) * DP + k0 + sg * 8, As + t * 512);
    }
    // Wm: 256 rows x 64 cols, 32 insts (8/wave)
#pragma unroll
    for (int i = 0; i < 8; i++) {
      int t = wave * 8 + i;
      gload_lds16(WmB + (size_t)(t * 8 + srow) * DP + k0 + sg * 8, Ws + t * 512);
    }
    __syncthreads();
#pragma unroll
    for (int kk = 0; kk < 2; kk++) {
      bf16x8_t af[4], bf[4];
#pragma unroll
      for (int im = 0; im < 4; im++)
        af[im] = *(const bf16x8_t*)(As + (im * 16 + ml) * 64 + kk * 32 + q * 8);
#pragma unroll
      for (int jn = 0; jn < 4; jn++)
        bf[jn] = *(const bf16x8_t*)(Ws + (wave * 64 + jn * 16 + ml) * 64 + kk * 32 + q * 8);
#pragma unroll
      for (int im = 0; im < 4; im++)
#pragma unroll
        for (int jn = 0; jn < 4; jn++)
          acc[im][jn] = __builtin_amdgcn_mfma_f32_16x16x32_bf16(
              af[im], bf[jn], acc[im][jn], 0, 0, 0);
    }
    __syncthreads();
  }

  // stage F rows (async into sF; disjoint from sS writes below)
#pragma unroll
  for (int i = 0; i < 8; i++) {
    int t = wave * 8 + i;  // rows t*2, t*2+1
    gload_lds16(featB + (size_t)(m0 + t * 2 + (lane >> 5)) * DP + (lane & 31) * 8,
                sF + t * 512);
  }
  // S -> LDS bf16. D[m][n]: n = lane&15(+tile), m = q*4+reg(+tile) [m89/m91]
#pragma unroll
  for (int im = 0; im < 4; im++)
#pragma unroll
    for (int jn = 0; jn < 4; jn++) {
      const int col = wave * 64 + jn * 16 + ml;
#pragma unroll
      for (int reg = 0; reg < 4; reg++)
        sS[(im * 16 + q * 4 + reg) * 256 + col] = f2bf(acc[im][jn][reg]);
    }
  __syncthreads();  // drains vmcnt (F staged) + sS visible

  // bracket: wave handles rows [wave*16, wave*16+16); lane owns k = lane+kk*64
#pragma unroll
  for (int kk = 0; kk < 4; kk++) {
    const int k = lane + kk * 64;
    int tb = 0, te = 0;
    if (k < D) { tb = rsK[k]; te = rsK[k + 1]; }
    for (int rr = 0; rr < 16; rr++) {
      const int r = wave * 16 + rr;
      float a = 0.f;
      for (int t = tb; t < te; t++) {
        int2 tr = trip[t];
        a += __int_as_float(tr.y) * bf2f(sS[r * 256 + (tr.x & 0xFFFF)]) *
             bf2f(sF[r * 256 + (tr.x >> 16)]);
      }
      if (m0 + r < N_NODES)
        agg[(size_t)(m0 + r) * DP + k] = __float2bfloat16(a);  // k>=D -> 0
    }
  }
}

// ---------------------------------------------------------------------------
// bf16 GEMM-NT via MFMA 16x16x32, async staging (R8-identical).
// EPI: 1 = +bias +silu, bf16 out; 2 = +bias(n<D), f32 out.
// ---------------------------------------------------------------------------
template <int EPI>
__global__ __launch_bounds__(256) void gemm_bf16(
    const unsigned short* __restrict__ A, const unsigned short* __restrict__ B,
    const float* __restrict__ bias, void* __restrict__ Cout,
    int M, int Nn, int K, int lda, int ldb, int ldc) {
  constexpr int BM = 128;
  __shared__ unsigned short As[BM * 64];
  __shared__ unsigned short Bs[64 * 64];
  const int tid = threadIdx.x;
  const int wave = tid >> 6;
  const int lane = tid & 63;
  const int wm = wave >> 1;
  const int wn = wave & 1;
  const int ml = lane & 15;
  const int q = lane >> 4;
  const int m0 = blockIdx.y * BM;
  const int n0 = blockIdx.x * 64;
  const int srow = lane >> 3;
  const int sg = lane & 7;

  f32x4_t acc[4][2];
#pragma unroll
  for (int i = 0; i < 4; i++)
#pragma unroll
    for (int j = 0; j < 2; j++) acc[i][j] = (f32x4_t)0.f;

  for (int k0 = 0; k0 < K; k0 += 64) {
#pragma unroll
    for (int i = 0; i < 4; i++) {
      int t = wave * 4 + i;
      gload_lds16(A + (size_t)(m0 + t * 8 + srow) * lda + k0 + sg * 8, As + t * 512);
    }
#pragma unroll
    for (int i = 0; i < 2; i++) {
      int t = wave * 2 + i;
      gload_lds16(B + (size_t)(n0 + t * 8 + srow) * ldb + k0 + sg * 8, Bs + t * 512);
    }
    __syncthreads();
#pragma unroll
    for (int kk = 0; kk < 2; kk++) {
      bf16x8_t a[4], b[2];
#pragma unroll
      for (int im = 0; im < 4; im++) {
        int row = wm * 64 + im * 16 + ml;
        a[im] = *(const bf16x8_t*)(As + row * 64 + (kk * 4 + q) * 8);
      }
#pragma unroll
      for (int jn = 0; jn < 2; jn++) {
        int row = wn * 32 + jn * 16 + ml;
        b[jn] = *(const bf16x8_t*)(Bs + row * 64 + (kk * 4 + q) * 8);
      }
#pragma unroll
      for (int im = 0; im < 4; im++)
#pragma unroll
        for (int jn = 0; jn < 2; jn++)
          acc[im][jn] = __builtin_amdgcn_mfma_f32_16x16x32_bf16(
              a[im], b[jn], acc[im][jn], 0, 0, 0);
    }
    __syncthreads();
  }

#pragma unroll
  for (int im = 0; im < 4; im++) {
#pragma unroll
    for (int jn = 0; jn < 2; jn++) {
      int gn = n0 + wn * 32 + jn * 16 + ml;
#pragma unroll
      for (int reg = 0; reg < 4; reg++) {
        int gm = m0 + wm * 64 + im * 16 + q * 4 + reg;
        if (gm >= M) continue;
        float v = acc[im][jn][reg];
        if (EPI == 1) {
          v += bias[gn];
          v = v / (1.f + __expf(-v));
          ((__hip_bfloat16*)Cout)[(size_t)gm * ldc + gn] = __float2bfloat16(v);
        } else {
          v += (gn < D) ? bias[gn] : 0.f;
          ((float*)Cout)[(size_t)gm * ldc + gn] = v;
        }
      }
    }
  }
}

// ---------------------------------------------------------------------------
// Residual + LayerNorm, wave-per-node (R8-identical)
// ---------------------------------------------------------------------------
__global__ __launch_bounds__(256) void ln_kernel(
    const float* __restrict__ x0, const float* __restrict__ h2,
    const float* __restrict__ gamma, const float* __restrict__ beta,
    float* __restrict__ out) {
  const int tid = threadIdx.x;
  const int wv = tid >> 6;
  const int lane = tid & 63;
  const int n = blockIdx.x * 4 + wv;

  float4 x = make_float4(0.f, 0.f, 0.f, 0.f);
  if (lane < 62) {
    float4 f = *(const float4*)(x0 + (size_t)n * D + lane * 4);
    float4 h = *(const float4*)(h2 + (size_t)n * DP + lane * 4);
    x = make_float4(f.x + h.x, f.y + h.y, f.z + h.z, f.w + h.w);
  }
  float s = x.x + x.y + x.z + x.w;
#pragma unroll
  for (int o = 32; o > 0; o >>= 1) s += __shfl_xor(s, o);
  const float mu = s * (1.f / (float)D);
  float4 xc = make_float4(x.x - mu, x.y - mu, x.z - mu, x.w - mu);
  float v = 0.f;
  if (lane < 62) v = xc.x * xc.x + xc.y * xc.y + xc.z * xc.z + xc.w * xc.w;
#pragma unroll
  for (int o = 32; o > 0; o >>= 1) v += __shfl_xor(v, o);
  const float rstd = rsqrtf(v * (1.f / (float)D) + LN_EPS);
  if (lane < 62) {
    float4 g = *(const float4*)(gamma + lane * 4);
    float4 b = *(const float4*)(beta + lane * 4);
    float4 o;
    o.x = xc.x * rstd * g.x + b.x;
    o.y = xc.y * rstd * g.y + b.y;
    o.z = xc.z * rstd * g.z + b.z;
    o.w = xc.w * rstd * g.w + b.w;
    *(float4*)(out + (size_t)n * D + lane * 4) = o;
  }
}

// ---------------------------------------------------------------------------
extern "C" void kernel_launch(void* const* d_in, const int* in_sizes, int n_in,
                              void* d_out, int out_size, void* d_ws, size_t ws_size,
                              hipStream_t stream) {
  const float* features = (const float*)d_in[0];
  const int*   ei       = (const int*)d_in[1];
  const float* W_msg    = (const float*)d_in[2];
  const float* W1       = (const float*)d_in[3];
  const float* b1       = (const float*)d_in[4];
  const float* W2       = (const float*)d_in[5];
  const float* b2       = (const float*)d_in[6];
  const float* gamma    = (const float*)d_in[7];
  const float* beta     = (const float*)d_in[8];
  const int*   Iv       = (const int*)d_in[9];
  const int*   Jv       = (const int*)d_in[10];
  const int*   Kv       = (const int*)d_in[11];
  const float* Cv       = (const float*)d_in[12];
  float* out = (float*)d_out;

  char* cur = (char*)d_ws;
  auto alloc = [&](size_t bytes) {
    char* p = cur;
    cur += (bytes + 255) & ~(size_t)255;
    return p;
  };
  const size_t NP = (size_t)N_NODES + PAD_ROWS;  // padded row count
  __hip_bfloat16* featB = (__hip_bfloat16*)alloc(NP * DP * 2);
  __hip_bfloat16* WmB   = (__hip_bfloat16*)alloc((size_t)DP * DP * 2);
  __hip_bfloat16* W1B   = (__hip_bfloat16*)alloc((size_t)HDIM * DP * 2);
  __hip_bfloat16* W2B   = (__hip_bfloat16*)alloc((size_t)DP * HDIM * 2);
  unsigned short* G     = (unsigned short*)alloc(NP * DP * 2);
  __hip_bfloat16* aggB  = (__hip_bfloat16*)alloc(NP * DP * 2);
  unsigned short* H1B   = (unsigned short*)alloc(NP * HDIM * 2);
  float*          H2    = (float*)alloc((size_t)N_NODES * DP * 4);
  int*  rsK  = (int*)alloc((D + 1) * 4);
  int2* trip = (int2*)alloc(NNZ * 8);
  int*  deg  = (int*)alloc(N_NODES * 4);
  int*  rs   = (int*)alloc((N_NODES + 1) * 4);
  int*  woff = (int*)alloc(N_NODES * 4);
  int*  esrc = (int*)alloc(N_EDGES * 4);

  dim3 blk(256);

  // 1) prep: casts + deg zero + triple CSR
  prep_kernel<<<PREP_BLOCKS, blk, 0, stream>>>(
      features, W_msg, W1, W2, featB, WmB, W1B, W2B, deg,
      Iv, Jv, Kv, Cv, rsK, trip);
  // 2) edge CSR by target
  hist_tgt<<<(N_EDGES + 255) / 256, blk, 0, stream>>>(ei, deg);
  scan_deg<<<1, blk, 0, stream>>>(deg, rs, woff);
  place_edges<<<(N_EDGES + 255) / 256, blk, 0, stream>>>(ei, woff, esrc);
  // 3) gather (R8-identical, high occupancy preserved)
  gather_G<<<N_NODES / 4, blk, 0, stream>>>(
      (const unsigned short*)featB, rs, esrc, G);
  // 4) fused GEMM1 + bracket: agg = bracket(G@Wm^T, featB)   (S never hits HBM)
  gemm1_bracket<<<(N_NODES + 63) / 64, blk, 0, stream>>>(
      G, (const unsigned short*)featB, (const unsigned short*)WmB,
      rsK, trip, aggB);
  // 5) H1 = silu(agg @ W1^T + b1)
  gemm_bf16<1><<<dim3(HDIM / 64, (N_NODES + 127) / 128), blk, 0, stream>>>(
      (const unsigned short*)aggB, (const unsigned short*)W1B, b1, H1B,
      N_NODES, HDIM, DP, DP, DP, HDIM);
  // 6) H2 = H1 @ W2^T + b2
  gemm_bf16<2><<<dim3(DP / 64, (N_NODES + 127) / 128), blk, 0, stream>>>(
      H1B, (const unsigned short*)W2B, b2, H2, N_NODES, DP, HDIM, HDIM, HDIM, DP);
  // 7) out = LN(features + H2)
  ln_kernel<<<N_NODES / 4, blk, 0, stream>>>(features, H2, gamma, beta, out);
}

// Round 11
// 235.736 us; speedup vs baseline: 1.4266x; 1.4266x over previous
//
#include <hip/hip_runtime.h>
#include <hip/hip_bf16.h>

#define N_NODES 10000
#define N_EDGES 100000
#define D 248
#define DP 256      // padded D
#define HDIM 512
#define NNZ 2480
#define LN_EPS 1e-5f
#define PAD_ROWS 128  // row padding so async A-staging overrun stays in our buffers

typedef __attribute__((ext_vector_type(8))) short bf16x8_t;
typedef __attribute__((ext_vector_type(4))) float f32x4_t;

__device__ __forceinline__ float bf2f(unsigned short u) {
  unsigned int x = ((unsigned int)u) << 16;
  return __builtin_bit_cast(float, x);
}
__device__ __forceinline__ unsigned short f2bf(float f) {
  return __builtin_bit_cast(unsigned short, __float2bfloat16(f));
}
__device__ __forceinline__ float bflo(unsigned int w) {
  return __builtin_bit_cast(float, w << 16);
}
__device__ __forceinline__ float bfhi(unsigned int w) {
  return __builtin_bit_cast(float, w & 0xFFFF0000u);
}
__device__ __forceinline__ void gload_lds16(const unsigned short* gp,
                                            unsigned short* lds_base) {
  __builtin_amdgcn_global_load_lds(
      (const __attribute__((address_space(1))) void*)gp,
      (__attribute__((address_space(3))) void*)lds_base, 16, 0, 0);
}

// ---------------------------------------------------------------------------
// Fused prep, decoded by blockIdx.x:
//   [0, 1250)        featB cast, 8 rows/block, float4->bf16x8 vectorized
//   [1250, +DP)      cast W_msg -> WmB (DP,DP)
//   [.., +HDIM)      cast W1 -> W1B (H,DP)
//   [.., +DP)        cast W2 -> W2B (DP,H)
//   [.., +40)        deg[i] = 0
//   last             CSR of triples by K (packed int2 {J<<16|I, C})
// ---------------------------------------------------------------------------
#define FEAT_BLOCKS 1250
#define WCAST_BLOCKS (DP + HDIM + DP)
#define ZERO_BLOCKS 40
#define PREP_BLOCKS (FEAT_BLOCKS + WCAST_BLOCKS + ZERO_BLOCKS + 1)

__device__ __forceinline__ void cast_row(const float* src, __hip_bfloat16* dst,
                                         int r, int sr, int sc, int dc) {
  for (int c = threadIdx.x; c < dc; c += 256) {
    float v = (r < sr && c < sc) ? src[(size_t)r * sc + c] : 0.f;
    dst[(size_t)r * dc + c] = __float2bfloat16(v);
  }
}

__global__ __launch_bounds__(256) void prep_kernel(
    const float* __restrict__ features, const float* __restrict__ W_msg,
    const float* __restrict__ W1, const float* __restrict__ W2,
    unsigned short* __restrict__ featB, __hip_bfloat16* __restrict__ WmB,
    __hip_bfloat16* __restrict__ W1B, __hip_bfloat16* __restrict__ W2B,
    int* __restrict__ deg,
    const int* __restrict__ Iv, const int* __restrict__ Jv,
    const int* __restrict__ Kv, const float* __restrict__ Cv,
    int* __restrict__ rsK, int2* __restrict__ trip) {
  const int b = blockIdx.x;
  const int tid = threadIdx.x;
  if (b < FEAT_BLOCKS) {
    // 8 rows/block; 32 lanes/row, lane c handles 8 cols (16B out, 32B in)
    const int r = b * 8 + (tid >> 5);
    const int c = tid & 31;
    uint4 o = make_uint4(0u, 0u, 0u, 0u);
    if (c < 31) {
      const float* src = features + (size_t)r * D + c * 8;
      float4 v0 = *(const float4*)(src);
      float4 v1 = *(const float4*)(src + 4);
      o.x = (unsigned)f2bf(v0.x) | ((unsigned)f2bf(v0.y) << 16);
      o.y = (unsigned)f2bf(v0.z) | ((unsigned)f2bf(v0.w) << 16);
      o.z = (unsigned)f2bf(v1.x) | ((unsigned)f2bf(v1.y) << 16);
      o.w = (unsigned)f2bf(v1.z) | ((unsigned)f2bf(v1.w) << 16);
    }
    *(uint4*)(featB + (size_t)r * DP + c * 8) = o;
  } else if (b < FEAT_BLOCKS + DP) {
    cast_row(W_msg, WmB, b - FEAT_BLOCKS, D, D, DP);
  } else if (b < FEAT_BLOCKS + DP + HDIM) {
    cast_row(W1, W1B, b - FEAT_BLOCKS - DP, HDIM, D, DP);
  } else if (b < FEAT_BLOCKS + WCAST_BLOCKS) {
    cast_row(W2, W2B, b - FEAT_BLOCKS - DP - HDIM, D, HDIM, HDIM);
  } else if (b < FEAT_BLOCKS + WCAST_BLOCKS + ZERO_BLOCKS) {
    int i = (b - FEAT_BLOCKS - WCAST_BLOCKS) * 256 + tid;
    if (i < N_NODES) deg[i] = 0;
  } else {
    __shared__ int cnt[D];
    __shared__ int off[D];
    for (int k = tid; k < D; k += 256) cnt[k] = 0;
    __syncthreads();
    for (int t = tid; t < NNZ; t += 256) atomicAdd(&cnt[Kv[t]], 1);
    __syncthreads();
    if (tid == 0) {
      int run = 0;
      for (int k = 0; k < D; k++) { off[k] = run; rsK[k] = run; run += cnt[k]; }
      rsK[D] = run;
    }
    __syncthreads();
    for (int t = tid; t < NNZ; t += 256) {
      int pos = atomicAdd(&off[Kv[t]], 1);
      trip[pos] = make_int2((Jv[t] << 16) | Iv[t], __float_as_int(Cv[t]));
    }
  }
}

// ---------------------------------------------------------------------------
// Edge CSR-by-target: histogram -> scan (emits int2 {beg,deg}) -> placement
// ---------------------------------------------------------------------------
__global__ __launch_bounds__(256) void hist_tgt(
    const int* __restrict__ ei, int* __restrict__ deg) {
  int e = blockIdx.x * 256 + threadIdx.x;
  if (e < N_EDGES) atomicAdd(&deg[ei[N_EDGES + e]], 1);
}

__global__ __launch_bounds__(256) void scan_deg(
    const int* __restrict__ deg, int2* __restrict__ rs2, int* __restrict__ woff) {
  __shared__ int part[256];
  const int t = threadIdx.x;
  const int base = t * 40;
  int sum = 0;
  for (int i = 0; i < 40; i++) {
    int idx = base + i;
    if (idx < N_NODES) sum += deg[idx];
  }
  part[t] = sum;
  __syncthreads();
  if (t == 0) {
    int run = 0;
    for (int i = 0; i < 256; i++) { int tmp = part[i]; part[i] = run; run += tmp; }
  }
  __syncthreads();
  int run = part[t];
  for (int i = 0; i < 40; i++) {
    int idx = base + i;
    if (idx < N_NODES) {
      int d = deg[idx];
      rs2[idx] = make_int2(run, d);
      woff[idx] = run;
      run += d;
    }
  }
}

__global__ __launch_bounds__(256) void place_edges(
    const int* __restrict__ ei, int* __restrict__ woff, int* __restrict__ esrc) {
  int e = blockIdx.x * 256 + threadIdx.x;
  if (e < N_EDGES) {
    int pos = atomicAdd(&woff[ei[N_EDGES + e]], 1);
    esrc[pos] = ei[e];
  }
}

// ---------------------------------------------------------------------------
// Gather: G[n] = sum_{e: tgt=n} featB[src(e)], HALF-WAVE per node.
// 8 nodes/block, grid 1250. Each 32-lane half streams its node's rows with
// 16B/lane uint4 loads, 2 edges in flight; rs2 int2 gives {beg,deg} in one hop.
// ---------------------------------------------------------------------------
__global__ __launch_bounds__(256) void gather_G(
    const unsigned short* __restrict__ FB, const int2* __restrict__ rs2,
    const int* __restrict__ esrc, unsigned short* __restrict__ G) {
  const int tid = threadIdx.x;
  const int lane = tid & 63;
  const int half = lane >> 5;
  const int c = lane & 31;
  const int n = blockIdx.x * 8 + (tid >> 5);  // grid 1250, exact

  const int2 rd = rs2[n];
  const int beg = rd.x, deg = rd.y;
  int eid = (c < deg) ? esrc[beg + c] : 0;

  float a[8] = {0.f, 0.f, 0.f, 0.f, 0.f, 0.f, 0.f, 0.f};
  const unsigned short* FBc = FB + (size_t)c * 8;
  const int dc = (deg < 32) ? deg : 32;
  int j = 0;
  for (; j + 2 <= dc; j += 2) {
    int s0 = __shfl(eid, half * 32 + j);
    int s1 = __shfl(eid, half * 32 + j + 1);
    uint4 u0 = *(const uint4*)(FBc + (size_t)s0 * DP);
    uint4 u1 = *(const uint4*)(FBc + (size_t)s1 * DP);
    a[0] += bflo(u0.x) + bflo(u1.x); a[1] += bfhi(u0.x) + bfhi(u1.x);
    a[2] += bflo(u0.y) + bflo(u1.y); a[3] += bfhi(u0.y) + bfhi(u1.y);
    a[4] += bflo(u0.z) + bflo(u1.z); a[5] += bfhi(u0.z) + bfhi(u1.z);
    a[6] += bflo(u0.w) + bflo(u1.w); a[7] += bfhi(u0.w) + bfhi(u1.w);
  }
  for (; j < deg; j++) {
    int s = (j < 32) ? __shfl(eid, half * 32 + j) : esrc[beg + j];
    uint4 u = *(const uint4*)(FBc + (size_t)s * DP);
    a[0] += bflo(u.x); a[1] += bfhi(u.x);
    a[2] += bflo(u.y); a[3] += bfhi(u.y);
    a[4] += bflo(u.z); a[5] += bfhi(u.z);
    a[6] += bflo(u.w); a[7] += bfhi(u.w);
  }
  uint4 o;
  o.x = (unsigned)f2bf(a[0]) | ((unsigned)f2bf(a[1]) << 16);
  o.y = (unsigned)f2bf(a[2]) | ((unsigned)f2bf(a[3]) << 16);
  o.z = (unsigned)f2bf(a[4]) | ((unsigned)f2bf(a[5]) << 16);
  o.w = (unsigned)f2bf(a[6]) | ((unsigned)f2bf(a[7]) << 16);
  *(uint4*)(G + (size_t)n * DP + c * 8) = o;  // c=31 writes zeros (featB pad=0)
}

// ---------------------------------------------------------------------------
// bf16 GEMM-NT via MFMA 16x16x32, async global_load_lds staging (R8-identical).
// EPI: 1 = +bias +silu bf16 out; 2 = +bias(n<D) f32 out; 3 = plain f32 out.
// ---------------------------------------------------------------------------
template <int EPI>
__global__ __launch_bounds__(256) void gemm_bf16(
    const unsigned short* __restrict__ A, const unsigned short* __restrict__ B,
    const float* __restrict__ bias, void* __restrict__ Cout,
    int M, int Nn, int K, int lda, int ldb, int ldc) {
  constexpr int BM = 128;
  __shared__ unsigned short As[BM * 64];
  __shared__ unsigned short Bs[64 * 64];
  const int tid = threadIdx.x;
  const int wave = tid >> 6;
  const int lane = tid & 63;
  const int wm = wave >> 1;
  const int wn = wave & 1;
  const int ml = lane & 15;
  const int q = lane >> 4;
  const int m0 = blockIdx.y * BM;
  const int n0 = blockIdx.x * 64;
  const int srow = lane >> 3;
  const int sg = lane & 7;

  f32x4_t acc[4][2];
#pragma unroll
  for (int i = 0; i < 4; i++)
#pragma unroll
    for (int j = 0; j < 2; j++) acc[i][j] = (f32x4_t)0.f;

  for (int k0 = 0; k0 < K; k0 += 64) {
#pragma unroll
    for (int i = 0; i < 4; i++) {
      int t = wave * 4 + i;
      gload_lds16(A + (size_t)(m0 + t * 8 + srow) * lda + k0 + sg * 8, As + t * 512);
    }
#pragma unroll
    for (int i = 0; i < 2; i++) {
      int t = wave * 2 + i;
      gload_lds16(B + (size_t)(n0 + t * 8 + srow) * ldb + k0 + sg * 8, Bs + t * 512);
    }
    __syncthreads();
#pragma unroll
    for (int kk = 0; kk < 2; kk++) {
      bf16x8_t a[4], b[2];
#pragma unroll
      for (int im = 0; im < 4; im++) {
        int row = wm * 64 + im * 16 + ml;
        a[im] = *(const bf16x8_t*)(As + row * 64 + (kk * 4 + q) * 8);
      }
#pragma unroll
      for (int jn = 0; jn < 2; jn++) {
        int row = wn * 32 + jn * 16 + ml;
        b[jn] = *(const bf16x8_t*)(Bs + row * 64 + (kk * 4 + q) * 8);
      }
#pragma unroll
      for (int im = 0; im < 4; im++)
#pragma unroll
        for (int jn = 0; jn < 2; jn++)
          acc[im][jn] = __builtin_amdgcn_mfma_f32_16x16x32_bf16(
              a[im], b[jn], acc[im][jn], 0, 0, 0);
    }
    __syncthreads();
  }

  // D[m][n]: n = lane&15, m = quad*4 + reg  [verified m89/m91]
#pragma unroll
  for (int im = 0; im < 4; im++) {
#pragma unroll
    for (int jn = 0; jn < 2; jn++) {
      int gn = n0 + wn * 32 + jn * 16 + ml;
#pragma unroll
      for (int reg = 0; reg < 4; reg++) {
        int gm = m0 + wm * 64 + im * 16 + q * 4 + reg;
        if (gm >= M) continue;
        float v = acc[im][jn][reg];
        if (EPI == 1) {
          v += bias[gn];
          v = v / (1.f + __expf(-v));
          ((__hip_bfloat16*)Cout)[(size_t)gm * ldc + gn] = __float2bfloat16(v);
        } else if (EPI == 2) {
          v += (gn < D) ? bias[gn] : 0.f;
          ((float*)Cout)[(size_t)gm * ldc + gn] = v;
        } else {
          ((float*)Cout)[(size_t)gm * ldc + gn] = v;
        }
      }
    }
  }
}

// ---------------------------------------------------------------------------
// Per-node bracket (R8-identical): S f32 + features f32 staged in LDS
// ---------------------------------------------------------------------------
__global__ __launch_bounds__(256) void bracket_kernel(
    const float* __restrict__ S, const float* __restrict__ F,
    const int* __restrict__ rsK, const int2* __restrict__ trip,
    __hip_bfloat16* __restrict__ agg) {
  __shared__ float sS[4][DP];
  __shared__ float sF[4][DP];
  const int tid = threadIdx.x;
  const int wv = tid >> 6;
  const int lane = tid & 63;
  const int n = blockIdx.x * 4 + wv;

  ((float4*)sS[wv])[lane] = ((const float4*)(S + (size_t)n * DP))[lane];
  if (lane < 62) ((float4*)sF[wv])[lane] = ((const float4*)(F + (size_t)n * D))[lane];
  __syncthreads();

  const float* Sr = sS[wv];
  const float* Fr = sF[wv];
#pragma unroll
  for (int kk = 0; kk < 4; kk++) {
    int k = lane + kk * 64;
    float a = 0.f;
    if (k < D) {
      const int b = rsK[k], e = rsK[k + 1];
      for (int t = b; t < e; t++) {
        int2 tr = trip[t];
        a += __int_as_float(tr.y) * Sr[tr.x & 0xFFFF] * Fr[tr.x >> 16];
      }
    }
    agg[(size_t)n * DP + k] = __float2bfloat16(a);
  }
}

// ---------------------------------------------------------------------------
// Residual + LayerNorm, wave-per-node (R8-identical)
// ---------------------------------------------------------------------------
__global__ __launch_bounds__(256) void ln_kernel(
    const float* __restrict__ x0, const float* __restrict__ h2,
    const float* __restrict__ gamma, const float* __restrict__ beta,
    float* __restrict__ out) {
  const int tid = threadIdx.x;
  const int wv = tid >> 6;
  const int lane = tid & 63;
  const int n = blockIdx.x * 4 + wv;

  float4 x = make_float4(0.f, 0.f, 0.f, 0.f);
  if (lane < 62) {
    float4 f = *(const float4*)(x0 + (size_t)n * D + lane * 4);
    float4 h = *(const float4*)(h2 + (size_t)n * DP + lane * 4);
    x = make_float4(f.x + h.x, f.y + h.y, f.z + h.z, f.w + h.w);
  }
  float s = x.x + x.y + x.z + x.w;
#pragma unroll
  for (int o = 32; o > 0; o >>= 1) s += __shfl_xor(s, o);
  const float mu = s * (1.f / (float)D);
  float4 xc = make_float4(x.x - mu, x.y - mu, x.z - mu, x.w - mu);
  float v = 0.f;
  if (lane < 62) v = xc.x * xc.x + xc.y * xc.y + xc.z * xc.z + xc.w * xc.w;
#pragma unroll
  for (int o = 32; o > 0; o >>= 1) v += __shfl_xor(v, o);
  const float rstd = rsqrtf(v * (1.f / (float)D) + LN_EPS);
  if (lane < 62) {
    float4 g = *(const float4*)(gamma + lane * 4);
    float4 b = *(const float4*)(beta + lane * 4);
    float4 o;
    o.x = xc.x * rstd * g.x + b.x;
    o.y = xc.y * rstd * g.y + b.y;
    o.z = xc.z * rstd * g.z + b.z;
    o.w = xc.w * rstd * g.w + b.w;
    *(float4*)(out + (size_t)n * D + lane * 4) = o;
  }
}

// ---------------------------------------------------------------------------
extern "C" void kernel_launch(void* const* d_in, const int* in_sizes, int n_in,
                              void* d_out, int out_size, void* d_ws, size_t ws_size,
                              hipStream_t stream) {
  const float* features = (const float*)d_in[0];
  const int*   ei       = (const int*)d_in[1];
  const float* W_msg    = (const float*)d_in[2];
  const float* W1       = (const float*)d_in[3];
  const float* b1       = (const float*)d_in[4];
  const float* W2       = (const float*)d_in[5];
  const float* b2       = (const float*)d_in[6];
  const float* gamma    = (const float*)d_in[7];
  const float* beta     = (const float*)d_in[8];
  const int*   Iv       = (const int*)d_in[9];
  const int*   Jv       = (const int*)d_in[10];
  const int*   Kv       = (const int*)d_in[11];
  const float* Cv       = (const float*)d_in[12];
  float* out = (float*)d_out;

  char* cur = (char*)d_ws;
  auto alloc = [&](size_t bytes) {
    char* p = cur;
    cur += (bytes + 255) & ~(size_t)255;
    return p;
  };
  const size_t NP = (size_t)N_NODES + PAD_ROWS;
  unsigned short* featB = (unsigned short*)alloc(NP * DP * 2);
  __hip_bfloat16* WmB   = (__hip_bfloat16*)alloc((size_t)DP * DP * 2);
  __hip_bfloat16* W1B   = (__hip_bfloat16*)alloc((size_t)HDIM * DP * 2);
  __hip_bfloat16* W2B   = (__hip_bfloat16*)alloc((size_t)DP * HDIM * 2);
  unsigned short* G     = (unsigned short*)alloc(NP * DP * 2);
  float*          S     = (float*)alloc((size_t)N_NODES * DP * 4);
  __hip_bfloat16* aggB  = (__hip_bfloat16*)alloc(NP * DP * 2);
  unsigned short* H1B   = (unsigned short*)alloc(NP * HDIM * 2);
  float*          H2    = S;  // alias: S dead once bracket has run
  int*  rsK  = (int*)alloc((D + 1) * 4);
  int2* trip = (int2*)alloc(NNZ * 8);
  int*  deg  = (int*)alloc(N_NODES * 4);
  int2* rs2  = (int2*)alloc((size_t)N_NODES * 8);
  int*  woff = (int*)alloc(N_NODES * 4);
  int*  esrc = (int*)alloc(N_EDGES * 4);

  dim3 blk(256);

  // 1) prep: vectorized feature cast + weight casts + deg zero + triple CSR
  prep_kernel<<<PREP_BLOCKS, blk, 0, stream>>>(
      features, W_msg, W1, W2, featB, WmB, W1B, W2B, deg,
      Iv, Jv, Kv, Cv, rsK, trip);
  // 2) edge CSR by target
  hist_tgt<<<(N_EDGES + 255) / 256, blk, 0, stream>>>(ei, deg);
  scan_deg<<<1, blk, 0, stream>>>(deg, rs2, woff);
  place_edges<<<(N_EDGES + 255) / 256, blk, 0, stream>>>(ei, woff, esrc);
  // 3) gather: half-wave per node
  gather_G<<<N_NODES / 8, blk, 0, stream>>>(featB, rs2, esrc, G);
  // 4) S = G @ Wm^T  (f32 out)
  gemm_bf16<3><<<dim3(DP / 64, (N_NODES + 127) / 128), blk, 0, stream>>>(
      G, (const unsigned short*)WmB, nullptr, S, N_NODES, DP, DP, DP, DP, DP);
  // 5) agg = bracket(S, features)
  bracket_kernel<<<N_NODES / 4, blk, 0, stream>>>(S, features, rsK, trip, aggB);
  // 6) H1 = silu(agg @ W1^T + b1)
  gemm_bf16<1><<<dim3(HDIM / 64, (N_NODES + 127) / 128), blk, 0, stream>>>(
      (const unsigned short*)aggB, (const unsigned short*)W1B, b1, H1B,
      N_NODES, HDIM, DP, DP, DP, HDIM);
  // 7) H2 = H1 @ W2^T + b2  (aliases S)
  gemm_bf16<2><<<dim3(DP / 64, (N_NODES + 127) / 128), blk, 0, stream>>>(
      H1B, (const unsigned short*)W2B, b2, H2, N_NODES, DP, HDIM, HDIM, HDIM, DP);
  // 8) out = LN(features + H2)
  ln_kernel<<<N_NODES / 4, blk, 0, stream>>>(features, H2, gamma, beta, out);
}

// Round 12
// 212.897 us; speedup vs baseline: 1.5797x; 1.1073x over previous
//
#include <hip/hip_runtime.h>
#include <hip/hip_bf16.h>
#include <hip/hip_fp16.h>

#define N_NODES 10000
#define N_EDGES 100000
#define D 248
#define DP 256      // padded D
#define HDIM 512
#define NNZ 2480
#define LN_EPS 1e-5f
#define PAD_ROWS 128  // row padding so async A-staging overrun stays in our buffers

typedef __attribute__((ext_vector_type(8))) short bf16x8_t;
typedef __attribute__((ext_vector_type(4))) float f32x4_t;

__device__ __forceinline__ float bf2f(unsigned short u) {
  unsigned int x = ((unsigned int)u) << 16;
  return __builtin_bit_cast(float, x);
}
__device__ __forceinline__ unsigned short f2bf(float f) {
  return __builtin_bit_cast(unsigned short, __float2bfloat16(f));
}
__device__ __forceinline__ float bflo(unsigned int w) {
  return __builtin_bit_cast(float, w << 16);
}
__device__ __forceinline__ float bfhi(unsigned int w) {
  return __builtin_bit_cast(float, w & 0xFFFF0000u);
}
__device__ __forceinline__ unsigned packh2(float a, float b) {
  return __builtin_bit_cast(unsigned, __floats2half2_rn(a, b));
}
__device__ __forceinline__ void gload_lds16(const unsigned short* gp,
                                            unsigned short* lds_base) {
  __builtin_amdgcn_global_load_lds(
      (const __attribute__((address_space(1))) void*)gp,
      (__attribute__((address_space(3))) void*)lds_base, 16, 0, 0);
}

// ---------------------------------------------------------------------------
// Fused prep (R11-identical): vectorized feature cast, weight casts, deg zero,
// triple CSR by K (packed int2 {J<<16|I, C}).
// ---------------------------------------------------------------------------
#define FEAT_BLOCKS 1250
#define WCAST_BLOCKS (DP + HDIM + DP)
#define ZERO_BLOCKS 40
#define PREP_BLOCKS (FEAT_BLOCKS + WCAST_BLOCKS + ZERO_BLOCKS + 1)

__device__ __forceinline__ void cast_row(const float* src, __hip_bfloat16* dst,
                                         int r, int sr, int sc, int dc) {
  for (int c = threadIdx.x; c < dc; c += 256) {
    float v = (r < sr && c < sc) ? src[(size_t)r * sc + c] : 0.f;
    dst[(size_t)r * dc + c] = __float2bfloat16(v);
  }
}

__global__ __launch_bounds__(256) void prep_kernel(
    const float* __restrict__ features, const float* __restrict__ W_msg,
    const float* __restrict__ W1, const float* __restrict__ W2,
    unsigned short* __restrict__ featB, __hip_bfloat16* __restrict__ WmB,
    __hip_bfloat16* __restrict__ W1B, __hip_bfloat16* __restrict__ W2B,
    int* __restrict__ deg,
    const int* __restrict__ Iv, const int* __restrict__ Jv,
    const int* __restrict__ Kv, const float* __restrict__ Cv,
    int* __restrict__ rsK, int2* __restrict__ trip) {
  const int b = blockIdx.x;
  const int tid = threadIdx.x;
  if (b < FEAT_BLOCKS) {
    const int r = b * 8 + (tid >> 5);
    const int c = tid & 31;
    uint4 o = make_uint4(0u, 0u, 0u, 0u);
    if (c < 31) {
      const float* src = features + (size_t)r * D + c * 8;
      float4 v0 = *(const float4*)(src);
      float4 v1 = *(const float4*)(src + 4);
      o.x = (unsigned)f2bf(v0.x) | ((unsigned)f2bf(v0.y) << 16);
      o.y = (unsigned)f2bf(v0.z) | ((unsigned)f2bf(v0.w) << 16);
      o.z = (unsigned)f2bf(v1.x) | ((unsigned)f2bf(v1.y) << 16);
      o.w = (unsigned)f2bf(v1.z) | ((unsigned)f2bf(v1.w) << 16);
    }
    *(uint4*)(featB + (size_t)r * DP + c * 8) = o;
  } else if (b < FEAT_BLOCKS + DP) {
    cast_row(W_msg, WmB, b - FEAT_BLOCKS, D, D, DP);
  } else if (b < FEAT_BLOCKS + DP + HDIM) {
    cast_row(W1, W1B, b - FEAT_BLOCKS - DP, HDIM, D, DP);
  } else if (b < FEAT_BLOCKS + WCAST_BLOCKS) {
    cast_row(W2, W2B, b - FEAT_BLOCKS - DP - HDIM, D, HDIM, HDIM);
  } else if (b < FEAT_BLOCKS + WCAST_BLOCKS + ZERO_BLOCKS) {
    int i = (b - FEAT_BLOCKS - WCAST_BLOCKS) * 256 + tid;
    if (i < N_NODES) deg[i] = 0;
  } else {
    __shared__ int cnt[D];
    __shared__ int off[D];
    for (int k = tid; k < D; k += 256) cnt[k] = 0;
    __syncthreads();
    for (int t = tid; t < NNZ; t += 256) atomicAdd(&cnt[Kv[t]], 1);
    __syncthreads();
    if (tid == 0) {
      int run = 0;
      for (int k = 0; k < D; k++) { off[k] = run; rsK[k] = run; run += cnt[k]; }
      rsK[D] = run;
    }
    __syncthreads();
    for (int t = tid; t < NNZ; t += 256) {
      int pos = atomicAdd(&off[Kv[t]], 1);
      trip[pos] = make_int2((Jv[t] << 16) | Iv[t], __float_as_int(Cv[t]));
    }
  }
}

// ---------------------------------------------------------------------------
// Edge CSR-by-target (R11-identical)
// ---------------------------------------------------------------------------
__global__ __launch_bounds__(256) void hist_tgt(
    const int* __restrict__ ei, int* __restrict__ deg) {
  int e = blockIdx.x * 256 + threadIdx.x;
  if (e < N_EDGES) atomicAdd(&deg[ei[N_EDGES + e]], 1);
}

__global__ __launch_bounds__(256) void scan_deg(
    const int* __restrict__ deg, int2* __restrict__ rs2, int* __restrict__ woff) {
  __shared__ int part[256];
  const int t = threadIdx.x;
  const int base = t * 40;
  int sum = 0;
  for (int i = 0; i < 40; i++) {
    int idx = base + i;
    if (idx < N_NODES) sum += deg[idx];
  }
  part[t] = sum;
  __syncthreads();
  if (t == 0) {
    int run = 0;
    for (int i = 0; i < 256; i++) { int tmp = part[i]; part[i] = run; run += tmp; }
  }
  __syncthreads();
  int run = part[t];
  for (int i = 0; i < 40; i++) {
    int idx = base + i;
    if (idx < N_NODES) {
      int d = deg[idx];
      rs2[idx] = make_int2(run, d);
      woff[idx] = run;
      run += d;
    }
  }
}

__global__ __launch_bounds__(256) void place_edges(
    const int* __restrict__ ei, int* __restrict__ woff, int* __restrict__ esrc) {
  int e = blockIdx.x * 256 + threadIdx.x;
  if (e < N_EDGES) {
    int pos = atomicAdd(&woff[ei[N_EDGES + e]], 1);
    esrc[pos] = ei[e];
  }
}

// ---------------------------------------------------------------------------
// Gather (R11-identical): half-wave per node, 16B/lane uint4 loads
// ---------------------------------------------------------------------------
__global__ __launch_bounds__(256) void gather_G(
    const unsigned short* __restrict__ FB, const int2* __restrict__ rs2,
    const int* __restrict__ esrc, unsigned short* __restrict__ G) {
  const int tid = threadIdx.x;
  const int lane = tid & 63;
  const int half = lane >> 5;
  const int c = lane & 31;
  const int n = blockIdx.x * 8 + (tid >> 5);

  const int2 rd = rs2[n];
  const int beg = rd.x, deg = rd.y;
  int eid = (c < deg) ? esrc[beg + c] : 0;

  float a[8] = {0.f, 0.f, 0.f, 0.f, 0.f, 0.f, 0.f, 0.f};
  const unsigned short* FBc = FB + (size_t)c * 8;
  const int dc = (deg < 32) ? deg : 32;
  int j = 0;
  for (; j + 2 <= dc; j += 2) {
    int s0 = __shfl(eid, half * 32 + j);
    int s1 = __shfl(eid, half * 32 + j + 1);
    uint4 u0 = *(const uint4*)(FBc + (size_t)s0 * DP);
    uint4 u1 = *(const uint4*)(FBc + (size_t)s1 * DP);
    a[0] += bflo(u0.x) + bflo(u1.x); a[1] += bfhi(u0.x) + bfhi(u1.x);
    a[2] += bflo(u0.y) + bflo(u1.y); a[3] += bfhi(u0.y) + bfhi(u1.y);
    a[4] += bflo(u0.z) + bflo(u1.z); a[5] += bfhi(u0.z) + bfhi(u1.z);
    a[6] += bflo(u0.w) + bflo(u1.w); a[7] += bfhi(u0.w) + bfhi(u1.w);
  }
  for (; j < deg; j++) {
    int s = (j < 32) ? __shfl(eid, half * 32 + j) : esrc[beg + j];
    uint4 u = *(const uint4*)(FBc + (size_t)s * DP);
    a[0] += bflo(u.x); a[1] += bfhi(u.x);
    a[2] += bflo(u.y); a[3] += bfhi(u.y);
    a[4] += bflo(u.z); a[5] += bfhi(u.z);
    a[6] += bflo(u.w); a[7] += bfhi(u.w);
  }
  uint4 o;
  o.x = (unsigned)f2bf(a[0]) | ((unsigned)f2bf(a[1]) << 16);
  o.y = (unsigned)f2bf(a[2]) | ((unsigned)f2bf(a[3]) << 16);
  o.z = (unsigned)f2bf(a[4]) | ((unsigned)f2bf(a[5]) << 16);
  o.w = (unsigned)f2bf(a[6]) | ((unsigned)f2bf(a[7]) << 16);
  *(uint4*)(G + (size_t)n * DP + c * 8) = o;
}

// ---------------------------------------------------------------------------
// bf16 GEMM-NT via MFMA 16x16x32, async staging (R8/R11-identical).
// EPI: 1 = +bias +silu bf16 out; 2 = +bias(n<D) f32 out; 3 = plain f32 out.
// ---------------------------------------------------------------------------
template <int EPI>
__global__ __launch_bounds__(256) void gemm_bf16(
    const unsigned short* __restrict__ A, const unsigned short* __restrict__ B,
    const float* __restrict__ bias, void* __restrict__ Cout,
    int M, int Nn, int K, int lda, int ldb, int ldc) {
  constexpr int BM = 128;
  __shared__ unsigned short As[BM * 64];
  __shared__ unsigned short Bs[64 * 64];
  const int tid = threadIdx.x;
  const int wave = tid >> 6;
  const int lane = tid & 63;
  const int wm = wave >> 1;
  const int wn = wave & 1;
  const int ml = lane & 15;
  const int q = lane >> 4;
  const int m0 = blockIdx.y * BM;
  const int n0 = blockIdx.x * 64;
  const int srow = lane >> 3;
  const int sg = lane & 7;

  f32x4_t acc[4][2];
#pragma unroll
  for (int i = 0; i < 4; i++)
#pragma unroll
    for (int j = 0; j < 2; j++) acc[i][j] = (f32x4_t)0.f;

  for (int k0 = 0; k0 < K; k0 += 64) {
#pragma unroll
    for (int i = 0; i < 4; i++) {
      int t = wave * 4 + i;
      gload_lds16(A + (size_t)(m0 + t * 8 + srow) * lda + k0 + sg * 8, As + t * 512);
    }
#pragma unroll
    for (int i = 0; i < 2; i++) {
      int t = wave * 2 + i;
      gload_lds16(B + (size_t)(n0 + t * 8 + srow) * ldb + k0 + sg * 8, Bs + t * 512);
    }
    __syncthreads();
#pragma unroll
    for (int kk = 0; kk < 2; kk++) {
      bf16x8_t a[4], b[2];
#pragma unroll
      for (int im = 0; im < 4; im++) {
        int row = wm * 64 + im * 16 + ml;
        a[im] = *(const bf16x8_t*)(As + row * 64 + (kk * 4 + q) * 8);
      }
#pragma unroll
      for (int jn = 0; jn < 2; jn++) {
        int row = wn * 32 + jn * 16 + ml;
        b[jn] = *(const bf16x8_t*)(Bs + row * 64 + (kk * 4 + q) * 8);
      }
#pragma unroll
      for (int im = 0; im < 4; im++)
#pragma unroll
        for (int jn = 0; jn < 2; jn++)
          acc[im][jn] = __builtin_amdgcn_mfma_f32_16x16x32_bf16(
              a[im], b[jn], acc[im][jn], 0, 0, 0);
    }
    __syncthreads();
  }

  // D[m][n]: n = lane&15, m = quad*4 + reg  [verified m89/m91]
#pragma unroll
  for (int im = 0; im < 4; im++) {
#pragma unroll
    for (int jn = 0; jn < 2; jn++) {
      int gn = n0 + wn * 32 + jn * 16 + ml;
#pragma unroll
      for (int reg = 0; reg < 4; reg++) {
        int gm = m0 + wm * 64 + im * 16 + q * 4 + reg;
        if (gm >= M) continue;
        float v = acc[im][jn][reg];
        if (EPI == 1) {
          v += bias[gn];
          v = v / (1.f + __expf(-v));
          ((__hip_bfloat16*)Cout)[(size_t)gm * ldc + gn] = __float2bfloat16(v);
        } else if (EPI == 2) {
          v += (gn < D) ? bias[gn] : 0.f;
          ((float*)Cout)[(size_t)gm * ldc + gn] = v;
        } else {
          ((float*)Cout)[(size_t)gm * ldc + gn] = v;
        }
      }
    }
  }
}

// ---------------------------------------------------------------------------
// Bracket, packed-f16 2-nodes-per-wave: S,F rows for a node PAIR live in LDS
// as half2 (lo=node0, hi=node1). Per triple: 2 ds_read_b32 + v_pk_mul_f16 +
// 2 f32 FMAs for BOTH nodes (half the LDS reads & trip loads of R11).
// Accumulation stays f32. 8 nodes/block, grid 1250.
// ---------------------------------------------------------------------------
__global__ __launch_bounds__(256) void bracket_kernel(
    const float* __restrict__ S, const float* __restrict__ F,
    const int* __restrict__ rsK, const int2* __restrict__ trip,
    __hip_bfloat16* __restrict__ agg) {
  __shared__ unsigned sS2[4][DP];  // half2-packed node pair
  __shared__ unsigned sF2[4][DP];
  const int tid = threadIdx.x;
  const int wv = tid >> 6;
  const int lane = tid & 63;
  const int n0 = blockIdx.x * 8 + wv * 2;
  const int n1 = n0 + 1;

  // stage S pair (DP cols, 64 lanes x 4 cols)
  {
    float4 s0 = ((const float4*)(S + (size_t)n0 * DP))[lane];
    float4 s1 = ((const float4*)(S + (size_t)n1 * DP))[lane];
    unsigned* d = &sS2[wv][lane * 4];
    d[0] = packh2(s0.x, s1.x);
    d[1] = packh2(s0.y, s1.y);
    d[2] = packh2(s0.z, s1.z);
    d[3] = packh2(s0.w, s1.w);
  }
  // stage F pair (D cols; lanes 62,63 zero the pad)
  {
    float4 f0 = make_float4(0.f, 0.f, 0.f, 0.f), f1 = f0;
    if (lane < 62) {
      f0 = *(const float4*)(F + (size_t)n0 * D + lane * 4);
      f1 = *(const float4*)(F + (size_t)n1 * D + lane * 4);
    }
    unsigned* d = &sF2[wv][lane * 4];
    d[0] = packh2(f0.x, f1.x);
    d[1] = packh2(f0.y, f1.y);
    d[2] = packh2(f0.z, f1.z);
    d[3] = packh2(f0.w, f1.w);
  }
  __syncthreads();

  const unsigned* S2 = sS2[wv];
  const unsigned* F2 = sF2[wv];
#pragma unroll
  for (int kk = 0; kk < 4; kk++) {
    const int k = lane + kk * 64;
    float a0 = 0.f, a1 = 0.f, b0 = 0.f, b1 = 0.f;
    if (k < D) {
      const int tb = rsK[k], te = rsK[k + 1];
      int t = tb;
      for (; t + 2 <= te; t += 2) {  // two independent chains vs LDS latency
        int2 t0 = trip[t], t1 = trip[t + 1];
        __half2 p0 = __hmul2(__builtin_bit_cast(__half2, S2[t0.x & 0xFFFF]),
                             __builtin_bit_cast(__half2, F2[t0.x >> 16]));
        __half2 p1 = __hmul2(__builtin_bit_cast(__half2, S2[t1.x & 0xFFFF]),
                             __builtin_bit_cast(__half2, F2[t1.x >> 16]));
        float2 q0 = __half22float2(p0);
        float2 q1 = __half22float2(p1);
        const float c0 = __int_as_float(t0.y), c1 = __int_as_float(t1.y);
        a0 += c0 * q0.x; a1 += c0 * q0.y;
        b0 += c1 * q1.x; b1 += c1 * q1.y;
      }
      if (t < te) {
        int2 t0 = trip[t];
        __half2 p0 = __hmul2(__builtin_bit_cast(__half2, S2[t0.x & 0xFFFF]),
                             __builtin_bit_cast(__half2, F2[t0.x >> 16]));
        float2 q0 = __half22float2(p0);
        const float c0 = __int_as_float(t0.y);
        a0 += c0 * q0.x; a1 += c0 * q0.y;
      }
    }
    agg[(size_t)n0 * DP + k] = __float2bfloat16(a0 + b0);  // k>=D -> 0 pad
    agg[(size_t)n1 * DP + k] = __float2bfloat16(a1 + b1);
  }
}

// ---------------------------------------------------------------------------
// Residual + LayerNorm, wave-per-node (R11-identical)
// ---------------------------------------------------------------------------
__global__ __launch_bounds__(256) void ln_kernel(
    const float* __restrict__ x0, const float* __restrict__ h2,
    const float* __restrict__ gamma, const float* __restrict__ beta,
    float* __restrict__ out) {
  const int tid = threadIdx.x;
  const int wv = tid >> 6;
  const int lane = tid & 63;
  const int n = blockIdx.x * 4 + wv;

  float4 x = make_float4(0.f, 0.f, 0.f, 0.f);
  if (lane < 62) {
    float4 f = *(const float4*)(x0 + (size_t)n * D + lane * 4);
    float4 h = *(const float4*)(h2 + (size_t)n * DP + lane * 4);
    x = make_float4(f.x + h.x, f.y + h.y, f.z + h.z, f.w + h.w);
  }
  float s = x.x + x.y + x.z + x.w;
#pragma unroll
  for (int o = 32; o > 0; o >>= 1) s += __shfl_xor(s, o);
  const float mu = s * (1.f / (float)D);
  float4 xc = make_float4(x.x - mu, x.y - mu, x.z - mu, x.w - mu);
  float v = 0.f;
  if (lane < 62) v = xc.x * xc.x + xc.y * xc.y + xc.z * xc.z + xc.w * xc.w;
#pragma unroll
  for (int o = 32; o > 0; o >>= 1) v += __shfl_xor(v, o);
  const float rstd = rsqrtf(v * (1.f / (float)D) + LN_EPS);
  if (lane < 62) {
    float4 g = *(const float4*)(gamma + lane * 4);
    float4 b = *(const float4*)(beta + lane * 4);
    float4 o;
    o.x = xc.x * rstd * g.x + b.x;
    o.y = xc.y * rstd * g.y + b.y;
    o.z = xc.z * rstd * g.z + b.z;
    o.w = xc.w * rstd * g.w + b.w;
    *(float4*)(out + (size_t)n * D + lane * 4) = o;
  }
}

// ---------------------------------------------------------------------------
extern "C" void kernel_launch(void* const* d_in, const int* in_sizes, int n_in,
                              void* d_out, int out_size, void* d_ws, size_t ws_size,
                              hipStream_t stream) {
  const float* features = (const float*)d_in[0];
  const int*   ei       = (const int*)d_in[1];
  const float* W_msg    = (const float*)d_in[2];
  const float* W1       = (const float*)d_in[3];
  const float* b1       = (const float*)d_in[4];
  const float* W2       = (const float*)d_in[5];
  const float* b2       = (const float*)d_in[6];
  const float* gamma    = (const float*)d_in[7];
  const float* beta     = (const float*)d_in[8];
  const int*   Iv       = (const int*)d_in[9];
  const int*   Jv       = (const int*)d_in[10];
  const int*   Kv       = (const int*)d_in[11];
  const float* Cv       = (const float*)d_in[12];
  float* out = (float*)d_out;

  char* cur = (char*)d_ws;
  auto alloc = [&](size_t bytes) {
    char* p = cur;
    cur += (bytes + 255) & ~(size_t)255;
    return p;
  };
  const size_t NP = (size_t)N_NODES + PAD_ROWS;
  unsigned short* featB = (unsigned short*)alloc(NP * DP * 2);
  __hip_bfloat16* WmB   = (__hip_bfloat16*)alloc((size_t)DP * DP * 2);
  __hip_bfloat16* W1B   = (__hip_bfloat16*)alloc((size_t)HDIM * DP * 2);
  __hip_bfloat16* W2B   = (__hip_bfloat16*)alloc((size_t)DP * HDIM * 2);
  unsigned short* G     = (unsigned short*)alloc(NP * DP * 2);
  float*          S     = (float*)alloc((size_t)N_NODES * DP * 4);
  __hip_bfloat16* aggB  = (__hip_bfloat16*)alloc(NP * DP * 2);
  unsigned short* H1B   = (unsigned short*)alloc(NP * HDIM * 2);
  float*          H2    = S;  // alias: S dead once bracket has run
  int*  rsK  = (int*)alloc((D + 1) * 4);
  int2* trip = (int2*)alloc(NNZ * 8);
  int*  deg  = (int*)alloc(N_NODES * 4);
  int2* rs2  = (int2*)alloc((size_t)N_NODES * 8);
  int*  woff = (int*)alloc(N_NODES * 4);
  int*  esrc = (int*)alloc(N_EDGES * 4);

  dim3 blk(256);

  // 1) prep
  prep_kernel<<<PREP_BLOCKS, blk, 0, stream>>>(
      features, W_msg, W1, W2, featB, WmB, W1B, W2B, deg,
      Iv, Jv, Kv, Cv, rsK, trip);
  // 2) edge CSR by target
  hist_tgt<<<(N_EDGES + 255) / 256, blk, 0, stream>>>(ei, deg);
  scan_deg<<<1, blk, 0, stream>>>(deg, rs2, woff);
  place_edges<<<(N_EDGES + 255) / 256, blk, 0, stream>>>(ei, woff, esrc);
  // 3) gather: half-wave per node
  gather_G<<<N_NODES / 8, blk, 0, stream>>>(featB, rs2, esrc, G);
  // 4) S = G @ Wm^T  (f32 out)
  gemm_bf16<3><<<dim3(DP / 64, (N_NODES + 127) / 128), blk, 0, stream>>>(
      G, (const unsigned short*)WmB, nullptr, S, N_NODES, DP, DP, DP, DP, DP);
  // 5) agg = bracket(S, features)  -- packed-f16 node pairs
  bracket_kernel<<<N_NODES / 8, blk, 0, stream>>>(S, features, rsK, trip, aggB);
  // 6) H1 = silu(agg @ W1^T + b1)
  gemm_bf16<1><<<dim3(HDIM / 64, (N_NODES + 127) / 128), blk, 0, stream>>>(
      (const unsigned short*)aggB, (const unsigned short*)W1B, b1, H1B,
      N_NODES, HDIM, DP, DP, DP, HDIM);
  // 7) H2 = H1 @ W2^T + b2  (aliases S)
  gemm_bf16<2><<<dim3(DP / 64, (N_NODES + 127) / 128), blk, 0, stream>>>(
      H1B, (const unsigned short*)W2B, b2, H2, N_NODES, DP, HDIM, HDIM, HDIM, DP);
  // 8) out = LN(features + H2)
  ln_kernel<<<N_NODES / 4, blk, 0, stream>>>(features, H2, gamma, beta, out);
}

// Round 13
// 212.220 us; speedup vs baseline: 1.5847x; 1.0032x over previous
//
#include <hip/hip_runtime.h>
#include <hip/hip_bf16.h>
#include <hip/hip_fp16.h>

#define N_NODES 10000
#define N_EDGES 100000
#define D 248
#define DP 256      // padded D
#define HDIM 512
#define NNZ 2480
#define LN_EPS 1e-5f
#define PAD_ROWS 128  // row padding so async A-staging overrun stays in our buffers

typedef __attribute__((ext_vector_type(8))) _Float16 f16x8_t;  // 8 f16 = 4 VGPRs
typedef __attribute__((ext_vector_type(4))) float f32x4_t;     // MFMA accum

__device__ __forceinline__ unsigned short f2h(float f) {
  return __builtin_bit_cast(unsigned short, __float2half(f));
}
__device__ __forceinline__ unsigned packh2(float a, float b) {
  return __builtin_bit_cast(unsigned, __floats2half2_rn(a, b));
}
__device__ __forceinline__ void gload_lds16(const unsigned short* gp,
                                            unsigned short* lds_base) {
  __builtin_amdgcn_global_load_lds(
      (const __attribute__((address_space(1))) void*)gp,
      (__attribute__((address_space(3))) void*)lds_base, 16, 0, 0);
}

// ---------------------------------------------------------------------------
// Fused prep: vectorized feature cast (f32->f16), weight casts (f16),
// deg zero, triple CSR by K (packed int2 {J<<16|I, C}).
// ---------------------------------------------------------------------------
#define FEAT_BLOCKS 1250
#define WCAST_BLOCKS (DP + HDIM + DP)
#define ZERO_BLOCKS 40
#define PREP_BLOCKS (FEAT_BLOCKS + WCAST_BLOCKS + ZERO_BLOCKS + 1)

__device__ __forceinline__ void cast_row(const float* src, unsigned short* dst,
                                         int r, int sr, int sc, int dc) {
  for (int c = threadIdx.x; c < dc; c += 256) {
    float v = (r < sr && c < sc) ? src[(size_t)r * sc + c] : 0.f;
    dst[(size_t)r * dc + c] = f2h(v);
  }
}

__global__ __launch_bounds__(256) void prep_kernel(
    const float* __restrict__ features, const float* __restrict__ W_msg,
    const float* __restrict__ W1, const float* __restrict__ W2,
    unsigned short* __restrict__ featH, unsigned short* __restrict__ WmH,
    unsigned short* __restrict__ W1H, unsigned short* __restrict__ W2H,
    int* __restrict__ deg,
    const int* __restrict__ Iv, const int* __restrict__ Jv,
    const int* __restrict__ Kv, const float* __restrict__ Cv,
    int* __restrict__ rsK, int2* __restrict__ trip) {
  const int b = blockIdx.x;
  const int tid = threadIdx.x;
  if (b < FEAT_BLOCKS) {
    const int r = b * 8 + (tid >> 5);
    const int c = tid & 31;
    uint4 o = make_uint4(0u, 0u, 0u, 0u);
    if (c < 31) {
      const float* src = features + (size_t)r * D + c * 8;
      float4 v0 = *(const float4*)(src);
      float4 v1 = *(const float4*)(src + 4);
      o.x = packh2(v0.x, v0.y);
      o.y = packh2(v0.z, v0.w);
      o.z = packh2(v1.x, v1.y);
      o.w = packh2(v1.z, v1.w);
    }
    *(uint4*)(featH + (size_t)r * DP + c * 8) = o;
  } else if (b < FEAT_BLOCKS + DP) {
    cast_row(W_msg, WmH, b - FEAT_BLOCKS, D, D, DP);
  } else if (b < FEAT_BLOCKS + DP + HDIM) {
    cast_row(W1, W1H, b - FEAT_BLOCKS - DP, HDIM, D, DP);
  } else if (b < FEAT_BLOCKS + WCAST_BLOCKS) {
    cast_row(W2, W2H, b - FEAT_BLOCKS - DP - HDIM, D, HDIM, HDIM);
  } else if (b < FEAT_BLOCKS + WCAST_BLOCKS + ZERO_BLOCKS) {
    int i = (b - FEAT_BLOCKS - WCAST_BLOCKS) * 256 + tid;
    if (i < N_NODES) deg[i] = 0;
  } else {
    __shared__ int cnt[D];
    __shared__ int off[D];
    for (int k = tid; k < D; k += 256) cnt[k] = 0;
    __syncthreads();
    for (int t = tid; t < NNZ; t += 256) atomicAdd(&cnt[Kv[t]], 1);
    __syncthreads();
    if (tid == 0) {
      int run = 0;
      for (int k = 0; k < D; k++) { off[k] = run; rsK[k] = run; run += cnt[k]; }
      rsK[D] = run;
    }
    __syncthreads();
    for (int t = tid; t < NNZ; t += 256) {
      int pos = atomicAdd(&off[Kv[t]], 1);
      trip[pos] = make_int2((Jv[t] << 16) | Iv[t], __float_as_int(Cv[t]));
    }
  }
}

// ---------------------------------------------------------------------------
// Edge CSR-by-target (R12-identical)
// ---------------------------------------------------------------------------
__global__ __launch_bounds__(256) void hist_tgt(
    const int* __restrict__ ei, int* __restrict__ deg) {
  int e = blockIdx.x * 256 + threadIdx.x;
  if (e < N_EDGES) atomicAdd(&deg[ei[N_EDGES + e]], 1);
}

__global__ __launch_bounds__(256) void scan_deg(
    const int* __restrict__ deg, int2* __restrict__ rs2, int* __restrict__ woff) {
  __shared__ int part[256];
  const int t = threadIdx.x;
  const int base = t * 40;
  int sum = 0;
  for (int i = 0; i < 40; i++) {
    int idx = base + i;
    if (idx < N_NODES) sum += deg[idx];
  }
  part[t] = sum;
  __syncthreads();
  if (t == 0) {
    int run = 0;
    for (int i = 0; i < 256; i++) { int tmp = part[i]; part[i] = run; run += tmp; }
  }
  __syncthreads();
  int run = part[t];
  for (int i = 0; i < 40; i++) {
    int idx = base + i;
    if (idx < N_NODES) {
      int d = deg[idx];
      rs2[idx] = make_int2(run, d);
      woff[idx] = run;
      run += d;
    }
  }
}

__global__ __launch_bounds__(256) void place_edges(
    const int* __restrict__ ei, int* __restrict__ woff, int* __restrict__ esrc) {
  int e = blockIdx.x * 256 + threadIdx.x;
  if (e < N_EDGES) {
    int pos = atomicAdd(&woff[ei[N_EDGES + e]], 1);
    esrc[pos] = ei[e];
  }
}

// ---------------------------------------------------------------------------
// Gather f16: G[n] = sum_{e: tgt=n} featH[src(e)], HALF-WAVE per node.
// Accumulation in packed __half2 -> 4 v_pk_add_f16 per edge (vs ~20 VALU bf16).
// 2-edge unroll for independent chains.
// ---------------------------------------------------------------------------
__global__ __launch_bounds__(256) void gather_G(
    const unsigned short* __restrict__ FH, const int2* __restrict__ rs2,
    const int* __restrict__ esrc, unsigned short* __restrict__ G) {
  const int tid = threadIdx.x;
  const int lane = tid & 63;
  const int half = lane >> 5;
  const int c = lane & 31;
  const int n = blockIdx.x * 8 + (tid >> 5);  // grid 1250, exact

  const int2 rd = rs2[n];
  const int beg = rd.x, deg = rd.y;
  int eid = (c < deg) ? esrc[beg + c] : 0;

  __half2 a0 = __floats2half2_rn(0.f, 0.f), a1 = a0, a2 = a0, a3 = a0;
  __half2 b0 = a0, b1 = a0, b2 = a0, b3 = a0;
  const unsigned short* FHc = FH + (size_t)c * 8;
  const int dc = (deg < 32) ? deg : 32;
  int j = 0;
  for (; j + 2 <= dc; j += 2) {
    int s0 = __shfl(eid, half * 32 + j);
    int s1 = __shfl(eid, half * 32 + j + 1);
    uint4 u0 = *(const uint4*)(FHc + (size_t)s0 * DP);
    uint4 u1 = *(const uint4*)(FHc + (size_t)s1 * DP);
    a0 = __hadd2(a0, __builtin_bit_cast(__half2, u0.x));
    a1 = __hadd2(a1, __builtin_bit_cast(__half2, u0.y));
    a2 = __hadd2(a2, __builtin_bit_cast(__half2, u0.z));
    a3 = __hadd2(a3, __builtin_bit_cast(__half2, u0.w));
    b0 = __hadd2(b0, __builtin_bit_cast(__half2, u1.x));
    b1 = __hadd2(b1, __builtin_bit_cast(__half2, u1.y));
    b2 = __hadd2(b2, __builtin_bit_cast(__half2, u1.z));
    b3 = __hadd2(b3, __builtin_bit_cast(__half2, u1.w));
  }
  for (; j < deg; j++) {
    int s = (j < 32) ? __shfl(eid, half * 32 + j) : esrc[beg + j];
    uint4 u = *(const uint4*)(FHc + (size_t)s * DP);
    a0 = __hadd2(a0, __builtin_bit_cast(__half2, u.x));
    a1 = __hadd2(a1, __builtin_bit_cast(__half2, u.y));
    a2 = __hadd2(a2, __builtin_bit_cast(__half2, u.z));
    a3 = __hadd2(a3, __builtin_bit_cast(__half2, u.w));
  }
  uint4 o;
  o.x = __builtin_bit_cast(unsigned, __hadd2(a0, b0));
  o.y = __builtin_bit_cast(unsigned, __hadd2(a1, b1));
  o.z = __builtin_bit_cast(unsigned, __hadd2(a2, b2));
  o.w = __builtin_bit_cast(unsigned, __hadd2(a3, b3));
  *(uint4*)(G + (size_t)n * DP + c * 8) = o;  // c=31 stays zero (featH pad=0)
}

// ---------------------------------------------------------------------------
// f16 GEMM-NT via MFMA 16x16x32_f16, async global_load_lds staging.
// EPI: 1 = +bias +silu f16 out; 2 = +bias(n<D) f32 out; 3 = plain f32 out.
// ---------------------------------------------------------------------------
template <int EPI>
__global__ __launch_bounds__(256) void gemm_f16(
    const unsigned short* __restrict__ A, const unsigned short* __restrict__ B,
    const float* __restrict__ bias, void* __restrict__ Cout,
    int M, int Nn, int K, int lda, int ldb, int ldc) {
  constexpr int BM = 128;
  __shared__ unsigned short As[BM * 64];
  __shared__ unsigned short Bs[64 * 64];
  const int tid = threadIdx.x;
  const int wave = tid >> 6;
  const int lane = tid & 63;
  const int wm = wave >> 1;
  const int wn = wave & 1;
  const int ml = lane & 15;
  const int q = lane >> 4;
  const int m0 = blockIdx.y * BM;
  const int n0 = blockIdx.x * 64;
  const int srow = lane >> 3;
  const int sg = lane & 7;

  f32x4_t acc[4][2];
#pragma unroll
  for (int i = 0; i < 4; i++)
#pragma unroll
    for (int j = 0; j < 2; j++) acc[i][j] = (f32x4_t)0.f;

  for (int k0 = 0; k0 < K; k0 += 64) {
#pragma unroll
    for (int i = 0; i < 4; i++) {
      int t = wave * 4 + i;
      gload_lds16(A + (size_t)(m0 + t * 8 + srow) * lda + k0 + sg * 8, As + t * 512);
    }
#pragma unroll
    for (int i = 0; i < 2; i++) {
      int t = wave * 2 + i;
      gload_lds16(B + (size_t)(n0 + t * 8 + srow) * ldb + k0 + sg * 8, Bs + t * 512);
    }
    __syncthreads();
#pragma unroll
    for (int kk = 0; kk < 2; kk++) {
      f16x8_t a[4], b[2];
#pragma unroll
      for (int im = 0; im < 4; im++) {
        int row = wm * 64 + im * 16 + ml;
        a[im] = *(const f16x8_t*)(As + row * 64 + (kk * 4 + q) * 8);
      }
#pragma unroll
      for (int jn = 0; jn < 2; jn++) {
        int row = wn * 32 + jn * 16 + ml;
        b[jn] = *(const f16x8_t*)(Bs + row * 64 + (kk * 4 + q) * 8);
      }
#pragma unroll
      for (int im = 0; im < 4; im++)
#pragma unroll
        for (int jn = 0; jn < 2; jn++)
          acc[im][jn] = __builtin_amdgcn_mfma_f32_16x16x32_f16(
              a[im], b[jn], acc[im][jn], 0, 0, 0);
    }
    __syncthreads();
  }

  // D[m][n]: n = lane&15, m = quad*4 + reg  [C/D layout dtype-independent]
#pragma unroll
  for (int im = 0; im < 4; im++) {
#pragma unroll
    for (int jn = 0; jn < 2; jn++) {
      int gn = n0 + wn * 32 + jn * 16 + ml;
#pragma unroll
      for (int reg = 0; reg < 4; reg++) {
        int gm = m0 + wm * 64 + im * 16 + q * 4 + reg;
        if (gm >= M) continue;
        float v = acc[im][jn][reg];
        if (EPI == 1) {
          v += bias[gn];
          v = v / (1.f + __expf(-v));
          ((unsigned short*)Cout)[(size_t)gm * ldc + gn] = f2h(v);
        } else if (EPI == 2) {
          v += (gn < D) ? bias[gn] : 0.f;
          ((float*)Cout)[(size_t)gm * ldc + gn] = v;
        } else {
          ((float*)Cout)[(size_t)gm * ldc + gn] = v;
        }
      }
    }
  }
}

// ---------------------------------------------------------------------------
// Bracket, packed-f16 2-nodes-per-wave (R12 core). F staged from featH (f16)
// by OR-packing; S (f32 from GEMM1) packed via cvt. agg written f16.
// ---------------------------------------------------------------------------
__global__ __launch_bounds__(256) void bracket_kernel(
    const float* __restrict__ S, const unsigned short* __restrict__ FH,
    const int* __restrict__ rsK, const int2* __restrict__ trip,
    unsigned short* __restrict__ agg) {
  __shared__ unsigned sS2[4][DP];  // half2-packed node pair
  __shared__ unsigned sF2[4][DP];
  const int tid = threadIdx.x;
  const int wv = tid >> 6;
  const int lane = tid & 63;
  const int n0 = blockIdx.x * 8 + wv * 2;
  const int n1 = n0 + 1;

  // stage S pair (f32 -> half2)
  {
    float4 s0 = ((const float4*)(S + (size_t)n0 * DP))[lane];
    float4 s1 = ((const float4*)(S + (size_t)n1 * DP))[lane];
    unsigned* d = &sS2[wv][lane * 4];
    d[0] = packh2(s0.x, s1.x);
    d[1] = packh2(s0.y, s1.y);
    d[2] = packh2(s0.z, s1.z);
    d[3] = packh2(s0.w, s1.w);
  }
  // stage F pair straight from f16 featH (pad cols already zero)
  {
    ushort4 u0 = *(const ushort4*)(FH + (size_t)n0 * DP + lane * 4);
    ushort4 u1 = *(const ushort4*)(FH + (size_t)n1 * DP + lane * 4);
    unsigned* d = &sF2[wv][lane * 4];
    d[0] = (unsigned)u0.x | ((unsigned)u1.x << 16);
    d[1] = (unsigned)u0.y | ((unsigned)u1.y << 16);
    d[2] = (unsigned)u0.z | ((unsigned)u1.z << 16);
    d[3] = (unsigned)u0.w | ((unsigned)u1.w << 16);
  }
  __syncthreads();

  const unsigned* S2 = sS2[wv];
  const unsigned* F2 = sF2[wv];
#pragma unroll
  for (int kk = 0; kk < 4; kk++) {
    const int k = lane + kk * 64;
    float a0 = 0.f, a1 = 0.f, b0 = 0.f, b1 = 0.f;
    if (k < D) {
      const int tb = rsK[k], te = rsK[k + 1];
      int t = tb;
      for (; t + 2 <= te; t += 2) {
        int2 t0 = trip[t], t1 = trip[t + 1];
        __half2 p0 = __hmul2(__builtin_bit_cast(__half2, S2[t0.x & 0xFFFF]),
                             __builtin_bit_cast(__half2, F2[t0.x >> 16]));
        __half2 p1 = __hmul2(__builtin_bit_cast(__half2, S2[t1.x & 0xFFFF]),
                             __builtin_bit_cast(__half2, F2[t1.x >> 16]));
        float2 q0 = __half22float2(p0);
        float2 q1 = __half22float2(p1);
        const float c0 = __int_as_float(t0.y), c1 = __int_as_float(t1.y);
        a0 += c0 * q0.x; a1 += c0 * q0.y;
        b0 += c1 * q1.x; b1 += c1 * q1.y;
      }
      if (t < te) {
        int2 t0 = trip[t];
        __half2 p0 = __hmul2(__builtin_bit_cast(__half2, S2[t0.x & 0xFFFF]),
                             __builtin_bit_cast(__half2, F2[t0.x >> 16]));
        float2 q0 = __half22float2(p0);
        const float c0 = __int_as_float(t0.y);
        a0 += c0 * q0.x; a1 += c0 * q0.y;
      }
    }
    agg[(size_t)n0 * DP + k] = f2h(a0 + b0);  // k>=D -> 0 pad
    agg[(size_t)n1 * DP + k] = f2h(a1 + b1);
  }
}

// ---------------------------------------------------------------------------
// Residual + LayerNorm, wave-per-node (R12-identical)
// ---------------------------------------------------------------------------
__global__ __launch_bounds__(256) void ln_kernel(
    const float* __restrict__ x0, const float* __restrict__ h2,
    const float* __restrict__ gamma, const float* __restrict__ beta,
    float* __restrict__ out) {
  const int tid = threadIdx.x;
  const int wv = tid >> 6;
  const int lane = tid & 63;
  const int n = blockIdx.x * 4 + wv;

  float4 x = make_float4(0.f, 0.f, 0.f, 0.f);
  if (lane < 62) {
    float4 f = *(const float4*)(x0 + (size_t)n * D + lane * 4);
    float4 h = *(const float4*)(h2 + (size_t)n * DP + lane * 4);
    x = make_float4(f.x + h.x, f.y + h.y, f.z + h.z, f.w + h.w);
  }
  float s = x.x + x.y + x.z + x.w;
#pragma unroll
  for (int o = 32; o > 0; o >>= 1) s += __shfl_xor(s, o);
  const float mu = s * (1.f / (float)D);
  float4 xc = make_float4(x.x - mu, x.y - mu, x.z - mu, x.w - mu);
  float v = 0.f;
  if (lane < 62) v = xc.x * xc.x + xc.y * xc.y + xc.z * xc.z + xc.w * xc.w;
#pragma unroll
  for (int o = 32; o > 0; o >>= 1) v += __shfl_xor(v, o);
  const float rstd = rsqrtf(v * (1.f / (float)D) + LN_EPS);
  if (lane < 62) {
    float4 g = *(const float4*)(gamma + lane * 4);
    float4 b = *(const float4*)(beta + lane * 4);
    float4 o;
    o.x = xc.x * rstd * g.x + b.x;
    o.y = xc.y * rstd * g.y + b.y;
    o.z = xc.z * rstd * g.z + b.z;
    o.w = xc.w * rstd * g.w + b.w;
    *(float4*)(out + (size_t)n * D + lane * 4) = o;
  }
}

// ---------------------------------------------------------------------------
extern "C" void kernel_launch(void* const* d_in, const int* in_sizes, int n_in,
                              void* d_out, int out_size, void* d_ws, size_t ws_size,
                              hipStream_t stream) {
  const float* features = (const float*)d_in[0];
  const int*   ei       = (const int*)d_in[1];
  const float* W_msg    = (const float*)d_in[2];
  const float* W1       = (const float*)d_in[3];
  const float* b1       = (const float*)d_in[4];
  const float* W2       = (const float*)d_in[5];
  const float* b2       = (const float*)d_in[6];
  const float* gamma    = (const float*)d_in[7];
  const float* beta     = (const float*)d_in[8];
  const int*   Iv       = (const int*)d_in[9];
  const int*   Jv       = (const int*)d_in[10];
  const int*   Kv       = (const int*)d_in[11];
  const float* Cv       = (const float*)d_in[12];
  float* out = (float*)d_out;

  char* cur = (char*)d_ws;
  auto alloc = [&](size_t bytes) {
    char* p = cur;
    cur += (bytes + 255) & ~(size_t)255;
    return p;
  };
  const size_t NP = (size_t)N_NODES + PAD_ROWS;
  unsigned short* featH = (unsigned short*)alloc(NP * DP * 2);
  unsigned short* WmH   = (unsigned short*)alloc((size_t)DP * DP * 2);
  unsigned short* W1H   = (unsigned short*)alloc((size_t)HDIM * DP * 2);
  unsigned short* W2H   = (unsigned short*)alloc((size_t)DP * HDIM * 2);
  unsigned short* G     = (unsigned short*)alloc(NP * DP * 2);
  float*          S     = (float*)alloc((size_t)N_NODES * DP * 4);
  unsigned short* aggH  = (unsigned short*)alloc(NP * DP * 2);
  unsigned short* H1H   = (unsigned short*)alloc(NP * HDIM * 2);
  float*          H2    = S;  // alias: S dead once bracket has run
  int*  rsK  = (int*)alloc((D + 1) * 4);
  int2* trip = (int2*)alloc(NNZ * 8);
  int*  deg  = (int*)alloc(N_NODES * 4);
  int2* rs2  = (int2*)alloc((size_t)N_NODES * 8);
  int*  woff = (int*)alloc(N_NODES * 4);
  int*  esrc = (int*)alloc(N_EDGES * 4);

  dim3 blk(256);

  // 1) prep
  prep_kernel<<<PREP_BLOCKS, blk, 0, stream>>>(
      features, W_msg, W1, W2, featH, WmH, W1H, W2H, deg,
      Iv, Jv, Kv, Cv, rsK, trip);
  // 2) edge CSR by target
  hist_tgt<<<(N_EDGES + 255) / 256, blk, 0, stream>>>(ei, deg);
  scan_deg<<<1, blk, 0, stream>>>(deg, rs2, woff);
  place_edges<<<(N_EDGES + 255) / 256, blk, 0, stream>>>(ei, woff, esrc);
  // 3) gather: half-wave per node, packed-f16 accumulation
  gather_G<<<N_NODES / 8, blk, 0, stream>>>(featH, rs2, esrc, G);
  // 4) S = G @ Wm^T  (f32 out)
  gemm_f16<3><<<dim3(DP / 64, (N_NODES + 127) / 128), blk, 0, stream>>>(
      G, WmH, nullptr, S, N_NODES, DP, DP, DP, DP, DP);
  // 5) agg = bracket(S, featH)  -- packed-f16 node pairs
  bracket_kernel<<<N_NODES / 8, blk, 0, stream>>>(S, featH, rsK, trip, aggH);
  // 6) H1 = silu(agg @ W1^T + b1)
  gemm_f16<1><<<dim3(HDIM / 64, (N_NODES + 127) / 128), blk, 0, stream>>>(
      aggH, W1H, b1, H1H, N_NODES, HDIM, DP, DP, DP, HDIM);
  // 7) H2 = H1 @ W2^T + b2  (aliases S)
  gemm_f16<2><<<dim3(DP / 64, (N_NODES + 127) / 128), blk, 0, stream>>>(
      H1H, W2H, b2, H2, N_NODES, DP, HDIM, HDIM, HDIM, DP);
  // 8) out = LN(features + H2)
  ln_kernel<<<N_NODES / 4, blk, 0, stream>>>(features, H2, gamma, beta, out);
}